// Round 12
// baseline (594.549 us; speedup 1.0000x reference)
//
#include <hip/hip_runtime.h>
#include <stdint.h>

#define N_NODES 50000
#define N_EDGES 800000
#define DIM 128
#define CAP 64     // padded adjacency slots/node; Poisson(16) => P(deg>=64) ~ 1e-26
#define NGRP 8     // dst-range groups for the scatter
#define GRPN (N_NODES / NGRP)  // 6250 nodes per group
#define BPG 250    // scatter blocks per group (2000 total)
#define BCAP 104448  // bucket capacity (100k mean, ~15 sigma headroom)
#define AGG_NPB 8  // nodes per block in k_agg (4 waves x 2 nodes)

// Feature tables are DIM-SLICED: elem (node,d) lives at
//   slice = d>>5, u16 index = slice*(N_NODES*32) + node*32 + (d&31)
// One slice = 50000*64B = 3.2 MB -> fits each XCD's 4 MB L2, so the random
// neighbor gathers in k_agg are L2-hits during that slice's phase.

typedef __bf16 bf16x8 __attribute__((ext_vector_type(8)));
typedef float f32x4 __attribute__((ext_vector_type(4)));
typedef unsigned uint4v __attribute__((ext_vector_type(4)));

// ---------------------------------------------------------------------------
// bf16 helpers (manual RNE pack; unpack = shift)
// ---------------------------------------------------------------------------
__device__ __forceinline__ unsigned short f2bf(float f) {
  unsigned u = __float_as_uint(f);
  unsigned r = u + 0x7fffu + ((u >> 16) & 1u);
  return (unsigned short)(r >> 16);
}
__device__ __forceinline__ unsigned pack2(float lo, float hi) {
  return (unsigned)f2bf(lo) | ((unsigned)f2bf(hi) << 16);
}
__device__ __forceinline__ float bf_lo(unsigned v) {
  return __uint_as_float(v << 16);
}
__device__ __forceinline__ float bf_hi(unsigned v) {
  return __uint_as_float(v & 0xffff0000u);
}

// Zero the 8 bucket counters (hipMemsetAsync fill dispatch is ~41us here).
__global__ void k_zero(int* __restrict__ bukCnt) {
  if (threadIdx.x < NGRP) bukCnt[threadIdx.x] = 0;
}

// ---------------------------------------------------------------------------
// Fused prep (one launch): block ranges do
//   [0, CONV)   : edge pack + 8-way dst-range BUCKETING (LDS-staged append)
//   [CONV,+X2B) : x fp32 -> bf16 packed, written DIM-SLICED
//   [..,+CNT)   : cnt zero
//   [..,+PW)    : W1,W2 fp32 [k][c] -> bf16 [c][k]
// ---------------------------------------------------------------------------
#define CONV_BLOCKS 782
#define X2B_BLOCKS 3125
#define CNT_BLOCKS 49
#define PW_BLOCKS 128
#define PREP_BLOCKS (CONV_BLOCKS + X2B_BLOCKS + CNT_BLOCKS + PW_BLOCKS)

__global__ __launch_bounds__(256) void k_prep(
    const void* __restrict__ eptr, unsigned* __restrict__ ebuk,
    int* __restrict__ bukCnt, const float* __restrict__ x,
    unsigned* __restrict__ xb, int* __restrict__ cnt,
    const float* __restrict__ W1, const float* __restrict__ W2,
    unsigned short* __restrict__ wt1, unsigned short* __restrict__ wt2) {
  const int b = blockIdx.x;
  const int tid = threadIdx.x;
  if (b < CONV_BLOCKS) {
    __shared__ unsigned stage[NGRP][256];
    __shared__ int lcnt[NGRP];
    __shared__ int gbase[NGRP];
    if (tid < NGRP) lcnt[tid] = 0;
    const unsigned* w = (const unsigned*)eptr;
    const unsigned hw = w[2 * (tid & 15) + 1];
    const bool is64 = (__ballot(hw == 0u) == ~0ull);
    __syncthreads();
    const int e0 = (b * 256 + tid) * 4;  // N_EDGES % 4 == 0
    unsigned sd[4];
    int ne = 0;
    if (e0 < N_EDGES) {
      if (is64) {
        const long long* p = (const long long*)eptr;
#pragma unroll
        for (int j = 0; j < 4; ++j)
          sd[j] = (unsigned)p[e0 + j] | ((unsigned)p[N_EDGES + e0 + j] << 16);
      } else {
        const unsigned* p = (const unsigned*)eptr;
#pragma unroll
        for (int j = 0; j < 4; ++j)
          sd[j] = p[e0 + j] | (p[N_EDGES + e0 + j] << 16);
      }
      ne = 4;
    }
    for (int j = 0; j < ne; ++j) {
      const int d = (int)(sd[j] >> 16);
      const int g = d / GRPN;
      const int pos = atomicAdd(&lcnt[g], 1);
      if (pos < 256) {
        stage[g][pos] = sd[j];
      } else {  // overflow fallback (P ~ 1e-29)
        const int gp = atomicAdd(&bukCnt[g], 1);
        if (gp < BCAP) ebuk[(size_t)g * BCAP + gp] = sd[j];
      }
    }
    __syncthreads();
    if (tid < NGRP) gbase[tid] = atomicAdd(&bukCnt[tid], min(lcnt[tid], 256));
    __syncthreads();
#pragma unroll
    for (int g = 0; g < NGRP; ++g) {
      const int c = min(lcnt[g], 256);
      for (int i = tid; i < c; i += 256) {
        const int gp = gbase[g] + i;
        if (gp < BCAP) ebuk[(size_t)g * BCAP + gp] = stage[g][i];
      }
    }
  } else if (b < CONV_BLOCKS + X2B_BLOCKS) {
    const int i = (b - CONV_BLOCKS) * 256 + tid;  // 8 consecutive dims each
    const float4 v0 = ((const float4*)x)[2 * i];
    const float4 v1 = ((const float4*)x)[2 * i + 1];
    uint4v o;
    o[0] = pack2(v0.x, v0.y);
    o[1] = pack2(v0.z, v0.w);
    o[2] = pack2(v1.x, v1.y);
    o[3] = pack2(v1.z, v1.w);
    // sliced write: node = i>>4, chunk q = i&15 (dims q*8..q*8+8)
    const int node = i >> 4;
    const int q = i & 15;
    ((uint4v*)xb)[(q >> 2) * (N_NODES * 4) + node * 4 + (q & 3)] = o;
  } else if (b < CONV_BLOCKS + X2B_BLOCKS + CNT_BLOCKS) {
    const int i = (b - CONV_BLOCKS - X2B_BLOCKS) * 256 + tid;
    if (i < N_NODES / 4) {
      uint4v z = {0u, 0u, 0u, 0u};
      ((uint4v*)cnt)[i] = z;
    }
  } else {
    const int i = (b - CONV_BLOCKS - X2B_BLOCKS - CNT_BLOCKS) * 256 + tid;
    const float* W = (i < DIM * DIM) ? W1 : W2;
    unsigned short* Wt = (i < DIM * DIM) ? wt1 : wt2;
    const int j = i & (DIM * DIM - 1);
    const int c = j >> 7, k = j & 127;
    Wt[c * DIM + k] = f2bf(W[k * DIM + c]);
  }
}

// ---------------------------------------------------------------------------
// Bucketed padded scatter (unchanged from round 9).
// ---------------------------------------------------------------------------
__global__ __launch_bounds__(256) void k_scatter(
    const unsigned* __restrict__ ebuk, const int* __restrict__ bukCnt,
    int* __restrict__ cnt, unsigned short* __restrict__ csrp) {
  const int grp = blockIdx.x & (NGRP - 1);
  const int slice = blockIdx.x >> 3;
  const int nE = min(bukCnt[grp], BCAP);
  const int CH = (nE + BPG - 1) / BPG;
  const int i0 = slice * CH;
  const int i1 = min(i0 + CH, nE);
  const unsigned* src = ebuk + (size_t)grp * BCAP;
  for (int i = i0 + (int)threadIdx.x; i < i1; i += 256) {
    const unsigned sd = src[i];
    const int d = (int)(sd >> 16);
    const int pos = atomicAdd(&cnt[d], 1);
    if (pos < CAP) csrp[(size_t)d * CAP + pos] = (unsigned short)(sd & 0xffffu);
  }
}

// ---------------------------------------------------------------------------
// DIM-SLICED aggregate: M[n,:] = (H[n,:] + sum_nb H[nb,:]) / (deg+1).
// Grid = 4 slices x (N/8) blocks, slice-major: resident blocks share one
// 3.2 MB slice -> neighbor gathers are per-XCD L2 hits (round-10 PMC showed
// the old full-row gather was L3-path-bound at 2.4 TB/s, MLP-insensitive).
// Wave: 16 lanes per row-slice x 4 neighbor groups; ids broadcast from a
// uniform uint4; 2 nodes interleaved; shfl_xor(16/32) group reduction.
// ---------------------------------------------------------------------------
__global__ __launch_bounds__(256) void k_agg(
    const unsigned* __restrict__ Hb, const unsigned short* __restrict__ csrp,
    const int* __restrict__ cnt, unsigned* __restrict__ Mb) {
  const int slice = blockIdx.x / (N_NODES / AGG_NPB);
  const int nb = blockIdx.x % (N_NODES / AGG_NPB);
  const int wid = threadIdx.x >> 6;
  const int lane = threadIdx.x & 63;
  const int l16 = lane & 15;
  const int j = lane >> 4;
  const int sh = (j & 1) << 4;  // u16 select within a word

  const unsigned* Hs = Hb + (size_t)slice * (N_NODES * 16);
  unsigned* Ms = Mb + (size_t)slice * (N_NODES * 16);

  const int nA = nb * AGG_NPB + wid * 2;
  const int nB = nA + 1;
  const int cA = cnt[nA], cB = cnt[nB];
  const int eA = min(cA, CAP), eB = min(cB, CAP);
  const unsigned short* lstA = csrp + (size_t)nA * CAP;
  const unsigned short* lstB = csrp + (size_t)nB * CAP;

  float ax = 0.f, ay = 0.f, bx = 0.f, by = 0.f;
  if (j == 0) {
    const unsigned sA = Hs[(size_t)nA * 16 + l16];
    const unsigned sB = Hs[(size_t)nB * 16 + l16];
    ax = bf_lo(sA); ay = bf_hi(sA);
    bx = bf_lo(sB); by = bf_hi(sB);
  }

  int kA = 0, kB = 0;
  while (true) {
    const bool dA = (kA + 8 <= eA), dB = (kB + 8 <= eB);
    if (!dA && !dB) break;
    unsigned vA1, vA2, vB1, vB2;
    if (dA) {  // 8 neighbors of A: group j handles #j and #(j+4)
      const uint4 q = *(const uint4*)(lstA + kA);
      const unsigned wl = (j & 2) ? q.y : q.x;
      const unsigned wh = (j & 2) ? q.w : q.z;
      vA1 = Hs[(size_t)((wl >> sh) & 0xffffu) * 16 + l16];
      vA2 = Hs[(size_t)((wh >> sh) & 0xffffu) * 16 + l16];
    }
    if (dB) {
      const uint4 q = *(const uint4*)(lstB + kB);
      const unsigned wl = (j & 2) ? q.y : q.x;
      const unsigned wh = (j & 2) ? q.w : q.z;
      vB1 = Hs[(size_t)((wl >> sh) & 0xffffu) * 16 + l16];
      vB2 = Hs[(size_t)((wh >> sh) & 0xffffu) * 16 + l16];
    }
    if (dA) {
      ax += bf_lo(vA1) + bf_lo(vA2);
      ay += bf_hi(vA1) + bf_hi(vA2);
      kA += 8;
    }
    if (dB) {
      bx += bf_lo(vB1) + bf_lo(vB2);
      by += bf_hi(vB1) + bf_hi(vB2);
      kB += 8;
    }
  }
  // 4-wide tails
  for (; kA + 4 <= eA; kA += 4) {
    const uint2 q2 = *(const uint2*)(lstA + kA);
    const unsigned wsel = (j & 2) ? q2.y : q2.x;
    const unsigned v = Hs[(size_t)((wsel >> sh) & 0xffffu) * 16 + l16];
    ax += bf_lo(v);
    ay += bf_hi(v);
  }
  for (; kB + 4 <= eB; kB += 4) {
    const uint2 q2 = *(const uint2*)(lstB + kB);
    const unsigned wsel = (j & 2) ? q2.y : q2.x;
    const unsigned v = Hs[(size_t)((wsel >> sh) & 0xffffu) * 16 + l16];
    bx += bf_lo(v);
    by += bf_hi(v);
  }
  // final 0-3 neighbors: group j takes neighbor kA+j
  if (j < eA - kA) {
    const unsigned v = Hs[(size_t)lstA[kA + j] * 16 + l16];
    ax += bf_lo(v);
    ay += bf_hi(v);
  }
  if (j < eB - kB) {
    const unsigned v = Hs[(size_t)lstB[kB + j] * 16 + l16];
    bx += bf_lo(v);
    by += bf_hi(v);
  }
  // reduce across the 4 groups (lane bits 4,5)
  ax += __shfl_xor(ax, 16); ax += __shfl_xor(ax, 32);
  ay += __shfl_xor(ay, 16); ay += __shfl_xor(ay, 32);
  bx += __shfl_xor(bx, 16); bx += __shfl_xor(bx, 32);
  by += __shfl_xor(by, 16); by += __shfl_xor(by, 32);
  if (j == 0) {
    const float idA = 1.0f / (float)(cA + 1);
    const float idB = 1.0f / (float)(cB + 1);
    Ms[(size_t)nA * 16 + l16] = pack2(ax * idA, ay * idA);
    Ms[(size_t)nB * 16 + l16] = pack2(bx * idB, by * idB);
  }
}

// ---------------------------------------------------------------------------
// H = relu(M @ W + b) via v_mfma_f32_16x16x32_bf16, sliced in/out.
// A-frag: slice ks holds dims ks*32+[0,32); lane l15 = row, lg*8 = k-offset.
// C/D: col = lane&15, row = 4*(lane>>4)+reg   [m89-verified layout]
// ---------------------------------------------------------------------------
__global__ __launch_bounds__(256) void k_gemm_mfma(
    const unsigned short* __restrict__ Mb, const unsigned short* __restrict__ Wt,
    const float* __restrict__ bias, unsigned short* __restrict__ Hb, int n) {
  const int lane = threadIdx.x & 63;
  const int wid = threadIdx.x >> 6;
  const int row0 = blockIdx.x * 64 + wid * 16;
  const int l15 = lane & 15;
  const int lg = lane >> 4;

  f32x4 acc[8];
#pragma unroll
  for (int t = 0; t < 8; ++t) {
    const float b = bias[t * 16 + l15];
    acc[t][0] = b; acc[t][1] = b; acc[t][2] = b; acc[t][3] = b;
  }

  const int arow = min(row0 + l15, n - 1);
  const unsigned short* aptr = Mb + (size_t)arow * 32 + lg * 8;
  const unsigned short* bbase = Wt + l15 * DIM + lg * 8;

#pragma unroll
  for (int ks = 0; ks < 4; ++ks) {
    const bf16x8 a = *(const bf16x8*)(aptr + (size_t)ks * (N_NODES * 32));
#pragma unroll
    for (int t = 0; t < 8; ++t) {
      const bf16x8 b = *(const bf16x8*)(bbase + t * 16 * DIM + ks * 32);
      acc[t] = __builtin_amdgcn_mfma_f32_16x16x32_bf16(a, b, acc[t], 0, 0, 0);
    }
  }

  const int orow0 = row0 + lg * 4;
#pragma unroll
  for (int r = 0; r < 4; ++r) {
    const int row = orow0 + r;
    if (row < n) {
#pragma unroll
      for (int t = 0; t < 8; ++t) {  // col = t*16+l15: slice t>>1
        Hb[(size_t)(t >> 1) * (N_NODES * 32) + (size_t)row * 32 +
           (t & 1) * 16 + l15] = f2bf(fmaxf(acc[t][r], 0.f));
      }
    }
  }
}

// ---------------------------------------------------------------------------
// out = alpha*scores + (1-alpha)*(relu(H @ Wh1 + bh1) @ Wh2 + bh2)
// H is sliced bf16.
// ---------------------------------------------------------------------------
#define ROW_FMA(J, V)                                                     \
  acc[J][0] = fmaf(V, w0.x, acc[J][0]);                                   \
  acc[J][1] = fmaf(V, w0.y, acc[J][1]);                                   \
  acc[J][2] = fmaf(V, w0.z, acc[J][2]);                                   \
  acc[J][3] = fmaf(V, w0.w, acc[J][3]);                                   \
  acc[J][4] = fmaf(V, w1.x, acc[J][4]);                                   \
  acc[J][5] = fmaf(V, w1.y, acc[J][5]);                                   \
  acc[J][6] = fmaf(V, w1.z, acc[J][6]);                                   \
  acc[J][7] = fmaf(V, w1.w, acc[J][7]);

__global__ __launch_bounds__(256) void k_head(
    const unsigned short* __restrict__ Hb, const float* __restrict__ Wh1,
    const float* __restrict__ bh1, const float* __restrict__ Wh2,
    const float* __restrict__ bh2, const float* __restrict__ scores,
    const float* __restrict__ alpha_logit, float* __restrict__ out, int n) {
  __shared__ float Wl[DIM * 64];  // 32 KiB, [k][c]
#pragma unroll
  for (int j = threadIdx.x; j < DIM * 64 / 4; j += 256)
    ((float4*)Wl)[j] = ((const float4*)Wh1)[j];
  __syncthreads();

  const int cg = threadIdx.x & 7;
  const int rg = threadIdx.x >> 3;
  const int row0 = blockIdx.x * 128 + rg * 4;

  const float alpha = 1.0f / (1.0f + __expf(-alpha_logit[0]));
  const float beta = 1.0f - alpha;
  const float bias2 = bh2[0];
  const float4 blo = *(const float4*)(bh1 + 4 * cg);
  const float4 bhi = *(const float4*)(bh1 + 32 + 4 * cg);
  const float4 w2lo = *(const float4*)(Wh2 + 4 * cg);
  const float4 w2hi = *(const float4*)(Wh2 + 32 + 4 * cg);

  float acc[4][8];
#pragma unroll
  for (int j = 0; j < 4; ++j) {
    acc[j][0] = blo.x; acc[j][1] = blo.y; acc[j][2] = blo.z; acc[j][3] = blo.w;
    acc[j][4] = bhi.x; acc[j][5] = bhi.y; acc[j][6] = bhi.z; acc[j][7] = bhi.w;
  }

  const int r0 = min(row0 + 0, n - 1), r1 = min(row0 + 1, n - 1);
  const int r2 = min(row0 + 2, n - 1), r3 = min(row0 + 3, n - 1);
  const uint2* hs = (const uint2*)Hb;  // uint2 = 4 bf16 dims
  const uint2* m0 = hs + (size_t)r0 * 8;
  const uint2* m1 = hs + (size_t)r1 * 8;
  const uint2* m2 = hs + (size_t)r2 * 8;
  const uint2* m3 = hs + (size_t)r3 * 8;

#pragma unroll
  for (int slice = 0; slice < 4; ++slice) {
#pragma unroll
    for (int k8 = 0; k8 < 8; ++k8) {
      const size_t idx = (size_t)slice * (N_NODES * 8) + k8;
      const uint2 u0 = m0[idx], u1 = m1[idx], u2 = m2[idx], u3 = m3[idx];
#pragma unroll
      for (int kk = 0; kk < 4; ++kk) {
        const float* wr = Wl + (slice * 32 + k8 * 4 + kk) * 64 + 4 * cg;
        const float4 w0 = *(const float4*)wr;
        const float4 w1 = *(const float4*)(wr + 32);
        const float v0 = (kk == 0) ? bf_lo(u0.x) : (kk == 1) ? bf_hi(u0.x)
                         : (kk == 2) ? bf_lo(u0.y) : bf_hi(u0.y);
        const float v1 = (kk == 0) ? bf_lo(u1.x) : (kk == 1) ? bf_hi(u1.x)
                         : (kk == 2) ? bf_lo(u1.y) : bf_hi(u1.y);
        const float v2 = (kk == 0) ? bf_lo(u2.x) : (kk == 1) ? bf_hi(u2.x)
                         : (kk == 2) ? bf_lo(u2.y) : bf_hi(u2.y);
        const float v3 = (kk == 0) ? bf_lo(u3.x) : (kk == 1) ? bf_hi(u3.x)
                         : (kk == 2) ? bf_lo(u3.y) : bf_hi(u3.y);
        ROW_FMA(0, v0)
        ROW_FMA(1, v1)
        ROW_FMA(2, v2)
        ROW_FMA(3, v3)
      }
    }
  }

#pragma unroll
  for (int j = 0; j < 4; ++j) {
    float s = fmaxf(acc[j][0], 0.f) * w2lo.x + fmaxf(acc[j][1], 0.f) * w2lo.y +
              fmaxf(acc[j][2], 0.f) * w2lo.z + fmaxf(acc[j][3], 0.f) * w2lo.w +
              fmaxf(acc[j][4], 0.f) * w2hi.x + fmaxf(acc[j][5], 0.f) * w2hi.y +
              fmaxf(acc[j][6], 0.f) * w2hi.z + fmaxf(acc[j][7], 0.f) * w2hi.w;
    s += __shfl_xor(s, 1);
    s += __shfl_xor(s, 2);
    s += __shfl_xor(s, 4);
    const int r = row0 + j;
    if (cg == 0 && r < n) out[r] = alpha * scores[r] + beta * (s + bias2);
  }
}

extern "C" void kernel_launch(void* const* d_in, const int* in_sizes, int n_in,
                              void* d_out, int out_size, void* d_ws,
                              size_t ws_size, hipStream_t stream) {
  const float* x      = (const float*)d_in[0];
  const void*  eidx   = d_in[1];
  const float* scores = (const float*)d_in[2];
  const float* W1     = (const float*)d_in[3];
  const float* b1     = (const float*)d_in[4];
  const float* W2     = (const float*)d_in[5];
  const float* b2     = (const float*)d_in[6];
  const float* Wh1    = (const float*)d_in[7];
  const float* bh1    = (const float*)d_in[8];
  const float* Wh2    = (const float*)d_in[9];
  const float* bh2    = (const float*)d_in[10];
  const float* alog   = (const float*)d_in[11];
  float* out = (float*)d_out;

  char* ws = (char*)d_ws;
  size_t off = 0;
  auto carve = [&](size_t bytes) -> char* {
    off = (off + 255) & ~(size_t)255;
    char* p = ws + off;
    off += bytes;
    return p;
  };
  unsigned short* csrp = (unsigned short*)carve((size_t)N_NODES * CAP * 2);
  unsigned* ebuk = (unsigned*)carve((size_t)NGRP * BCAP * 4);
  int*   bukCnt  = (int*)carve(NGRP * 4);
  int*   cnt     = (int*)carve((size_t)N_NODES * 4);
  unsigned* xb   = (unsigned*)carve((size_t)N_NODES * DIM * 2);
  unsigned* mb   = (unsigned*)carve((size_t)N_NODES * DIM * 2);
  unsigned* hb   = (unsigned*)carve((size_t)N_NODES * DIM * 2);
  unsigned short* wt1 = (unsigned short*)carve((size_t)DIM * DIM * 2);
  unsigned short* wt2 = (unsigned short*)carve((size_t)DIM * DIM * 2);

  k_zero<<<1, 64, 0, stream>>>(bukCnt);
  k_prep<<<PREP_BLOCKS, 256, 0, stream>>>(eidx, ebuk, bukCnt, x, xb, cnt, W1,
                                          W2, wt1, wt2);
  k_scatter<<<NGRP * BPG, 256, 0, stream>>>(ebuk, bukCnt, cnt, csrp);

  const int ablocks = 4 * (N_NODES / AGG_NPB);  // 25000, slice-major
  const int gblocks = (N_NODES + 63) / 64;      // 782
  const int hblocks = (N_NODES + 127) / 128;    // 391

  k_agg<<<ablocks, 256, 0, stream>>>(xb, csrp, cnt, mb);
  k_gemm_mfma<<<gblocks, 256, 0, stream>>>((const unsigned short*)mb, wt1, b1,
                                           (unsigned short*)hb, N_NODES);
  k_agg<<<ablocks, 256, 0, stream>>>(hb, csrp, cnt, mb);
  k_gemm_mfma<<<gblocks, 256, 0, stream>>>((const unsigned short*)mb, wt2, b2,
                                           (unsigned short*)hb, N_NODES);
  k_head<<<hblocks, 256, 0, stream>>>((const unsigned short*)hb, Wh1, bh1, Wh2,
                                      bh2, scores, alog, out, N_NODES);
}

// Round 13
// 177.459 us; speedup vs baseline: 3.3504x; 3.3504x over previous
//
#include <hip/hip_runtime.h>
#include <stdint.h>

#define N_NODES 50000
#define N_EDGES 800000
#define DIM 128
#define CAP 64     // padded adjacency slots/node; Poisson(16) => P(deg>=64) ~ 1e-26
#define NGRP 8     // dst-range groups for the scatter
#define GRPN (N_NODES / NGRP)  // 6250 nodes per group
#define BPG 250    // scatter blocks per group (2000 total)
#define BCAP 104448  // bucket capacity (100k mean, ~15 sigma headroom)

typedef __bf16 bf16x8 __attribute__((ext_vector_type(8)));
typedef float f32x4 __attribute__((ext_vector_type(4)));
typedef unsigned uint4v __attribute__((ext_vector_type(4)));

// ---------------------------------------------------------------------------
// bf16 helpers (manual RNE pack; unpack = shift)
// ---------------------------------------------------------------------------
__device__ __forceinline__ unsigned short f2bf(float f) {
  unsigned u = __float_as_uint(f);
  unsigned r = u + 0x7fffu + ((u >> 16) & 1u);
  return (unsigned short)(r >> 16);
}
__device__ __forceinline__ unsigned pack2(float lo, float hi) {
  return (unsigned)f2bf(lo) | ((unsigned)f2bf(hi) << 16);
}
__device__ __forceinline__ float bf_lo(unsigned v) {
  return __uint_as_float(v << 16);
}
__device__ __forceinline__ float bf_hi(unsigned v) {
  return __uint_as_float(v & 0xffff0000u);
}

// Zero the 8 bucket counters (hipMemsetAsync fill dispatch is ~41us here).
__global__ void k_zero(int* __restrict__ bukCnt) {
  if (threadIdx.x < NGRP) bukCnt[threadIdx.x] = 0;
}

// ---------------------------------------------------------------------------
// Fused prep (one launch): block ranges do
//   [0, CONV)   : edge pack + 8-way dst-range BUCKETING (LDS-staged append)
//   [CONV,+X2B) : x fp32 -> bf16 packed (8 floats/thread), ROW-MAJOR
//   [..,+CNT)   : cnt zero
//   [..,+PW)    : W1,W2 fp32 [k][c] -> bf16 [c][k]; Wh1 [k][h] -> bf16 [h][k]
// ---------------------------------------------------------------------------
#define CONV_BLOCKS 782
#define X2B_BLOCKS 3125
#define CNT_BLOCKS 49
#define PW_BLOCKS 160  // 2*128*128 + 128*64 = 40960 elems
#define PREP_BLOCKS (CONV_BLOCKS + X2B_BLOCKS + CNT_BLOCKS + PW_BLOCKS)

__global__ __launch_bounds__(256) void k_prep(
    const void* __restrict__ eptr, unsigned* __restrict__ ebuk,
    int* __restrict__ bukCnt, const float* __restrict__ x,
    unsigned* __restrict__ xb, int* __restrict__ cnt,
    const float* __restrict__ W1, const float* __restrict__ W2,
    const float* __restrict__ Wh1, unsigned short* __restrict__ wt1,
    unsigned short* __restrict__ wt2, unsigned short* __restrict__ wh1t) {
  const int b = blockIdx.x;
  const int tid = threadIdx.x;
  if (b < CONV_BLOCKS) {
    __shared__ unsigned stage[NGRP][256];
    __shared__ int lcnt[NGRP];
    __shared__ int gbase[NGRP];
    if (tid < NGRP) lcnt[tid] = 0;
    const unsigned* w = (const unsigned*)eptr;
    const unsigned hw = w[2 * (tid & 15) + 1];
    const bool is64 = (__ballot(hw == 0u) == ~0ull);
    __syncthreads();
    const int e0 = (b * 256 + tid) * 4;  // N_EDGES % 4 == 0
    unsigned sd[4];
    int ne = 0;
    if (e0 < N_EDGES) {
      if (is64) {
        const long long* p = (const long long*)eptr;
#pragma unroll
        for (int j = 0; j < 4; ++j)
          sd[j] = (unsigned)p[e0 + j] | ((unsigned)p[N_EDGES + e0 + j] << 16);
      } else {
        const unsigned* p = (const unsigned*)eptr;
#pragma unroll
        for (int j = 0; j < 4; ++j)
          sd[j] = p[e0 + j] | (p[N_EDGES + e0 + j] << 16);
      }
      ne = 4;
    }
    for (int j = 0; j < ne; ++j) {
      const int d = (int)(sd[j] >> 16);
      const int g = d / GRPN;
      const int pos = atomicAdd(&lcnt[g], 1);
      if (pos < 256) {
        stage[g][pos] = sd[j];
      } else {  // overflow fallback (P ~ 1e-29)
        const int gp = atomicAdd(&bukCnt[g], 1);
        if (gp < BCAP) ebuk[(size_t)g * BCAP + gp] = sd[j];
      }
    }
    __syncthreads();
    if (tid < NGRP) gbase[tid] = atomicAdd(&bukCnt[tid], min(lcnt[tid], 256));
    __syncthreads();
#pragma unroll
    for (int g = 0; g < NGRP; ++g) {
      const int c = min(lcnt[g], 256);
      for (int i = tid; i < c; i += 256) {
        const int gp = gbase[g] + i;
        if (gp < BCAP) ebuk[(size_t)g * BCAP + gp] = stage[g][i];
      }
    }
  } else if (b < CONV_BLOCKS + X2B_BLOCKS) {
    const int i = (b - CONV_BLOCKS) * 256 + tid;  // 8 floats each, exact
    const float4 v0 = ((const float4*)x)[2 * i];
    const float4 v1 = ((const float4*)x)[2 * i + 1];
    uint4v o;
    o[0] = pack2(v0.x, v0.y);
    o[1] = pack2(v0.z, v0.w);
    o[2] = pack2(v1.x, v1.y);
    o[3] = pack2(v1.z, v1.w);
    ((uint4v*)xb)[i] = o;
  } else if (b < CONV_BLOCKS + X2B_BLOCKS + CNT_BLOCKS) {
    const int i = (b - CONV_BLOCKS - X2B_BLOCKS) * 256 + tid;
    if (i < N_NODES / 4) {
      uint4v z = {0u, 0u, 0u, 0u};
      ((uint4v*)cnt)[i] = z;
    }
  } else {
    const int i = (b - CONV_BLOCKS - X2B_BLOCKS - CNT_BLOCKS) * 256 + tid;
    if (i < 2 * DIM * DIM) {
      const float* W = (i < DIM * DIM) ? W1 : W2;
      unsigned short* Wt = (i < DIM * DIM) ? wt1 : wt2;
      const int j = i & (DIM * DIM - 1);
      const int c = j >> 7, k = j & 127;
      Wt[c * DIM + k] = f2bf(W[k * DIM + c]);
    } else {
      const int j = i - 2 * DIM * DIM;  // 0..8191
      const int k = j >> 6, h = j & 63;
      wh1t[h * DIM + k] = f2bf(Wh1[k * 64 + h]);
    }
  }
}

// ---------------------------------------------------------------------------
// Bucketed padded scatter: group g = blockIdx&7 reads only bucket g and owns
// dst range [g*6250,(g+1)*6250) -> per-XCD working set ~1.2 MB.
// ---------------------------------------------------------------------------
__global__ __launch_bounds__(256) void k_scatter(
    const unsigned* __restrict__ ebuk, const int* __restrict__ bukCnt,
    int* __restrict__ cnt, unsigned short* __restrict__ csrp) {
  const int grp = blockIdx.x & (NGRP - 1);
  const int slice = blockIdx.x >> 3;
  const int nE = min(bukCnt[grp], BCAP);
  const int CH = (nE + BPG - 1) / BPG;
  const int i0 = slice * CH;
  const int i1 = min(i0 + CH, nE);
  const unsigned* src = ebuk + (size_t)grp * BCAP;
  for (int i = i0 + (int)threadIdx.x; i < i1; i += 256) {
    const unsigned sd = src[i];
    const int d = (int)(sd >> 16);
    const int pos = atomicAdd(&cnt[d], 1);
    if (pos < CAP) csrp[(size_t)d * CAP + pos] = (unsigned short)(sd & 0xffffu);
  }
}

// ---------------------------------------------------------------------------
// M[i,:] = (H[i,:] + sum_{j in N(i)} H[j,:]) / (deg+1), bf16 in/out,
// ROW-MAJOR (round-9 proven version; near gather-path roofline:
// 82 MB compulsory L2 fills @ ~2.4 TB/s).
// ---------------------------------------------------------------------------
__global__ __launch_bounds__(256) void k_agg(
    const unsigned* __restrict__ Hb, const unsigned short* __restrict__ csrp,
    const int* __restrict__ cnt, unsigned* __restrict__ Mb) {
  const int node = blockIdx.x * 4 + (threadIdx.x >> 6);  // grid = N/4 exact
  const int lane = threadIdx.x & 63;
  const unsigned self = Hb[(size_t)node * 64 + lane];
  float ax = bf_lo(self), ay = bf_hi(self);
  const int c = cnt[node];
  const int e = min(c, CAP);
  const unsigned short* lst = csrp + (size_t)node * CAP;
  int k = 0;
  for (; k + 8 <= e; k += 8) {
    const uint4 c8 = *(const uint4*)(lst + k);
    const int n0 = c8.x & 0xffff, n1 = c8.x >> 16;
    const int n2 = c8.y & 0xffff, n3 = c8.y >> 16;
    const int n4 = c8.z & 0xffff, n5 = c8.z >> 16;
    const int n6 = c8.w & 0xffff, n7 = c8.w >> 16;
    const unsigned v0 = Hb[(size_t)n0 * 64 + lane];
    const unsigned v1 = Hb[(size_t)n1 * 64 + lane];
    const unsigned v2 = Hb[(size_t)n2 * 64 + lane];
    const unsigned v3 = Hb[(size_t)n3 * 64 + lane];
    const unsigned v4 = Hb[(size_t)n4 * 64 + lane];
    const unsigned v5 = Hb[(size_t)n5 * 64 + lane];
    const unsigned v6 = Hb[(size_t)n6 * 64 + lane];
    const unsigned v7 = Hb[(size_t)n7 * 64 + lane];
    ax += bf_lo(v0) + bf_lo(v1) + bf_lo(v2) + bf_lo(v3) + bf_lo(v4) +
          bf_lo(v5) + bf_lo(v6) + bf_lo(v7);
    ay += bf_hi(v0) + bf_hi(v1) + bf_hi(v2) + bf_hi(v3) + bf_hi(v4) +
          bf_hi(v5) + bf_hi(v6) + bf_hi(v7);
  }
  for (; k < e; ++k) {
    const unsigned v = Hb[(size_t)lst[k] * 64 + lane];
    ax += bf_lo(v);
    ay += bf_hi(v);
  }
  const float id = 1.0f / (float)(c + 1);
  Mb[(size_t)node * 64 + lane] = pack2(ax * id, ay * id);
}

// ---------------------------------------------------------------------------
// Layer-1 GEMM: H = relu(M @ W + b) via v_mfma_f32_16x16x32_bf16, row-major.
// C/D: col = lane&15, row = 4*(lane>>4)+reg   [m89-verified layout]
// ---------------------------------------------------------------------------
__global__ __launch_bounds__(256) void k_gemm_mfma(
    const unsigned short* __restrict__ Mb, const unsigned short* __restrict__ Wt,
    const float* __restrict__ bias, unsigned short* __restrict__ Hb, int n) {
  const int lane = threadIdx.x & 63;
  const int wid = threadIdx.x >> 6;
  const int row0 = blockIdx.x * 64 + wid * 16;
  const int l15 = lane & 15;
  const int lg = lane >> 4;

  f32x4 acc[8];
#pragma unroll
  for (int t = 0; t < 8; ++t) {
    const float b = bias[t * 16 + l15];
    acc[t][0] = b; acc[t][1] = b; acc[t][2] = b; acc[t][3] = b;
  }

  const int arow = min(row0 + l15, n - 1);
  const unsigned short* aptr = Mb + (size_t)arow * DIM + lg * 8;
  const unsigned short* bbase = Wt + l15 * DIM + lg * 8;

#pragma unroll
  for (int ks = 0; ks < 4; ++ks) {
    const bf16x8 a = *(const bf16x8*)(aptr + ks * 32);
#pragma unroll
    for (int t = 0; t < 8; ++t) {
      const bf16x8 b = *(const bf16x8*)(bbase + t * 16 * DIM + ks * 32);
      acc[t] = __builtin_amdgcn_mfma_f32_16x16x32_bf16(a, b, acc[t], 0, 0, 0);
    }
  }

  const int orow0 = row0 + lg * 4;
#pragma unroll
  for (int r = 0; r < 4; ++r) {
    const int row = orow0 + r;
    if (row < n) {
#pragma unroll
      for (int t = 0; t < 8; ++t) {
        Hb[(size_t)row * DIM + t * 16 + l15] = f2bf(fmaxf(acc[t][r], 0.f));
      }
    }
  }
}

// ---------------------------------------------------------------------------
// FUSED layer-2 GEMM + head:
//   H = relu(M @ W2 + b2)            (32 MFMA, H kept on-chip)
//   H -> LDS (wave-private 16x128 tile, pad 136 u16 -> ~2-way read conflict)
//   P = relu(H @ Wh1 + bh1)          (16 MFMA via pre-transposed bf16 Wh1)
//   adj = P @ Wh2 + bh2              (4 fmul + shfl_xor reduce over 16 lanes)
//   out = alpha*scores + (1-alpha)*adj
// Saves 25.6 MB of hb round-trip + the k_head launch (round-11 lesson: keep
// unroll small, no runtime-indexed arrays -> no spill).
// ---------------------------------------------------------------------------
__global__ __launch_bounds__(256) void k_gemm_head(
    const unsigned short* __restrict__ Mb, const unsigned short* __restrict__ Wt,
    const float* __restrict__ bias, const unsigned short* __restrict__ Wh1t,
    const float* __restrict__ bh1, const float* __restrict__ Wh2,
    const float* __restrict__ bh2, const float* __restrict__ scores,
    const float* __restrict__ alpha_logit, float* __restrict__ out, int n) {
  __shared__ alignas(16) unsigned short Hl[4][16 * 136];
  const int lane = threadIdx.x & 63;
  const int wid = threadIdx.x >> 6;
  const int row0 = blockIdx.x * 64 + wid * 16;
  const int l15 = lane & 15;
  const int lg = lane >> 4;

  // ---- phase 1: H = relu(M @ W2 + b2), 16 rows x 128 cols in regs ----
  f32x4 acc[8];
#pragma unroll
  for (int t = 0; t < 8; ++t) {
    const float b = bias[t * 16 + l15];
    acc[t][0] = b; acc[t][1] = b; acc[t][2] = b; acc[t][3] = b;
  }
  const int arow = min(row0 + l15, n - 1);
  const unsigned short* aptr = Mb + (size_t)arow * DIM + lg * 8;
  const unsigned short* bbase = Wt + l15 * DIM + lg * 8;
#pragma unroll
  for (int ks = 0; ks < 4; ++ks) {
    const bf16x8 a = *(const bf16x8*)(aptr + ks * 32);
#pragma unroll
    for (int t = 0; t < 8; ++t) {
      const bf16x8 b = *(const bf16x8*)(bbase + t * 16 * DIM + ks * 32);
      acc[t] = __builtin_amdgcn_mfma_f32_16x16x32_bf16(a, b, acc[t], 0, 0, 0);
    }
  }

  // ---- H tile -> LDS (wave-private; pad to 136 u16/row) ----
  unsigned short* hl = Hl[wid];
#pragma unroll
  for (int r = 0; r < 4; ++r) {
    const int rl = lg * 4 + r;
#pragma unroll
    for (int t = 0; t < 8; ++t)
      hl[rl * 136 + t * 16 + l15] = f2bf(fmaxf(acc[t][r], 0.f));
  }
  __syncthreads();

  // ---- phase 2: P = relu(H @ Wh1 + bh1), 16 rows x 64 cols, K=128 ----
  f32x4 acc2[4];
#pragma unroll
  for (int t2 = 0; t2 < 4; ++t2) {
    const float b = bh1[t2 * 16 + l15];
    acc2[t2][0] = b; acc2[t2][1] = b; acc2[t2][2] = b; acc2[t2][3] = b;
  }
  const unsigned short* arow2 = hl + l15 * 136 + lg * 8;
  const unsigned short* bbase2 = Wh1t + l15 * DIM + lg * 8;
#pragma unroll
  for (int ks = 0; ks < 4; ++ks) {
    const bf16x8 a2 = *(const bf16x8*)(arow2 + ks * 32);
#pragma unroll
    for (int t2 = 0; t2 < 4; ++t2) {
      const bf16x8 b2 = *(const bf16x8*)(bbase2 + t2 * 16 * DIM + ks * 32);
      acc2[t2] = __builtin_amdgcn_mfma_f32_16x16x32_bf16(a2, b2, acc2[t2], 0, 0, 0);
    }
  }

  // ---- phase 3: adj = P @ Wh2 + bh2; blend with scores ----
  const float alpha = 1.0f / (1.0f + __expf(-alpha_logit[0]));
  const float beta = 1.0f - alpha;
  const float bias2 = bh2[0];
  float w2s0 = Wh2[l15], w2s1 = Wh2[16 + l15], w2s2 = Wh2[32 + l15],
        w2s3 = Wh2[48 + l15];
#pragma unroll
  for (int r = 0; r < 4; ++r) {
    float s = fmaxf(acc2[0][r], 0.f) * w2s0 + fmaxf(acc2[1][r], 0.f) * w2s1 +
              fmaxf(acc2[2][r], 0.f) * w2s2 + fmaxf(acc2[3][r], 0.f) * w2s3;
    s += __shfl_xor(s, 1);
    s += __shfl_xor(s, 2);
    s += __shfl_xor(s, 4);
    s += __shfl_xor(s, 8);
    const int row = row0 + lg * 4 + r;
    if (l15 == 0 && row < n)
      out[row] = alpha * scores[row] + beta * (s + bias2);
  }
}

extern "C" void kernel_launch(void* const* d_in, const int* in_sizes, int n_in,
                              void* d_out, int out_size, void* d_ws,
                              size_t ws_size, hipStream_t stream) {
  const float* x      = (const float*)d_in[0];
  const void*  eidx   = d_in[1];
  const float* scores = (const float*)d_in[2];
  const float* W1     = (const float*)d_in[3];
  const float* b1     = (const float*)d_in[4];
  const float* W2     = (const float*)d_in[5];
  const float* b2     = (const float*)d_in[6];
  const float* Wh1    = (const float*)d_in[7];
  const float* bh1    = (const float*)d_in[8];
  const float* Wh2    = (const float*)d_in[9];
  const float* bh2    = (const float*)d_in[10];
  const float* alog   = (const float*)d_in[11];
  float* out = (float*)d_out;

  char* ws = (char*)d_ws;
  size_t off = 0;
  auto carve = [&](size_t bytes) -> char* {
    off = (off + 255) & ~(size_t)255;
    char* p = ws + off;
    off += bytes;
    return p;
  };
  unsigned short* csrp = (unsigned short*)carve((size_t)N_NODES * CAP * 2);
  unsigned* ebuk = (unsigned*)carve((size_t)NGRP * BCAP * 4);
  int*   bukCnt  = (int*)carve(NGRP * 4);
  int*   cnt     = (int*)carve((size_t)N_NODES * 4);
  unsigned* xb   = (unsigned*)carve((size_t)N_NODES * DIM * 2);
  unsigned* mb   = (unsigned*)carve((size_t)N_NODES * DIM * 2);
  unsigned* hb   = (unsigned*)carve((size_t)N_NODES * DIM * 2);
  unsigned short* wt1  = (unsigned short*)carve((size_t)DIM * DIM * 2);
  unsigned short* wt2  = (unsigned short*)carve((size_t)DIM * DIM * 2);
  unsigned short* wh1t = (unsigned short*)carve((size_t)DIM * 64 * 2);

  k_zero<<<1, 64, 0, stream>>>(bukCnt);
  k_prep<<<PREP_BLOCKS, 256, 0, stream>>>(eidx, ebuk, bukCnt, x, xb, cnt, W1,
                                          W2, Wh1, wt1, wt2, wh1t);
  k_scatter<<<NGRP * BPG, 256, 0, stream>>>(ebuk, bukCnt, cnt, csrp);

  const int ablocks = N_NODES / 4;           // 12500
  const int gblocks = (N_NODES + 63) / 64;   // 782

  k_agg<<<ablocks, 256, 0, stream>>>(xb, csrp, cnt, mb);
  k_gemm_mfma<<<gblocks, 256, 0, stream>>>((const unsigned short*)mb, wt1, b1,
                                           (unsigned short*)hb, N_NODES);
  k_agg<<<ablocks, 256, 0, stream>>>(hb, csrp, cnt, mb);
  k_gemm_head<<<gblocks, 256, 0, stream>>>((const unsigned short*)mb, wt2, b2,
                                           wh1t, bh1, Wh2, bh2, scores, alog,
                                           out, N_NODES);
}

// Round 14
// 177.053 us; speedup vs baseline: 3.3580x; 1.0023x over previous
//
#include <hip/hip_runtime.h>
#include <stdint.h>

#define N_NODES 50000
#define N_EDGES 800000
#define DIM 128
#define CAP 64     // padded adjacency slots/node; Poisson(16) => P(deg>=64) ~ 1e-26
#define NGRP 8     // dst-range groups for the scatter
#define GRPN (N_NODES / NGRP)  // 6250 nodes per group
#define BPG 250    // scatter blocks per group (2000 total)
#define BCAP 104448  // bucket capacity (100k mean, ~15 sigma headroom)

typedef __bf16 bf16x8 __attribute__((ext_vector_type(8)));
typedef float f32x4 __attribute__((ext_vector_type(4)));
typedef unsigned uint4v __attribute__((ext_vector_type(4)));

// ---------------------------------------------------------------------------
// bf16 helpers (manual RNE pack; unpack = shift)
// ---------------------------------------------------------------------------
__device__ __forceinline__ unsigned short f2bf(float f) {
  unsigned u = __float_as_uint(f);
  unsigned r = u + 0x7fffu + ((u >> 16) & 1u);
  return (unsigned short)(r >> 16);
}
__device__ __forceinline__ unsigned pack2(float lo, float hi) {
  return (unsigned)f2bf(lo) | ((unsigned)f2bf(hi) << 16);
}
__device__ __forceinline__ float bf_lo(unsigned v) {
  return __uint_as_float(v << 16);
}
__device__ __forceinline__ float bf_hi(unsigned v) {
  return __uint_as_float(v & 0xffff0000u);
}

// Zero the 8 bucket counters (hipMemsetAsync fill dispatch is ~41us here).
__global__ void k_zero(int* __restrict__ bukCnt) {
  if (threadIdx.x < NGRP) bukCnt[threadIdx.x] = 0;
}

// ---------------------------------------------------------------------------
// Fused prep (one launch): block ranges do
//   [0, CONV)   : edge pack + 8-way dst-range BUCKETING (LDS-staged append)
//   [CONV,+X2B) : x fp32 -> bf16 packed (8 floats/thread), ROW-MAJOR
//   [..,+CNT)   : cnt zero
//   [..,+PW)    : W1,W2 fp32 [k][c] -> bf16 [c][k]; Wh1 [k][h] -> bf16 [h][k]
// ---------------------------------------------------------------------------
#define CONV_BLOCKS 782
#define X2B_BLOCKS 3125
#define CNT_BLOCKS 49
#define PW_BLOCKS 160  // 2*128*128 + 128*64 = 40960 elems
#define PREP_BLOCKS (CONV_BLOCKS + X2B_BLOCKS + CNT_BLOCKS + PW_BLOCKS)

__global__ __launch_bounds__(256) void k_prep(
    const void* __restrict__ eptr, unsigned* __restrict__ ebuk,
    int* __restrict__ bukCnt, const float* __restrict__ x,
    unsigned* __restrict__ xb, int* __restrict__ cnt,
    const float* __restrict__ W1, const float* __restrict__ W2,
    const float* __restrict__ Wh1, unsigned short* __restrict__ wt1,
    unsigned short* __restrict__ wt2, unsigned short* __restrict__ wh1t) {
  const int b = blockIdx.x;
  const int tid = threadIdx.x;
  if (b < CONV_BLOCKS) {
    __shared__ unsigned stage[NGRP][256];
    __shared__ int lcnt[NGRP];
    __shared__ int gbase[NGRP];
    if (tid < NGRP) lcnt[tid] = 0;
    const unsigned* w = (const unsigned*)eptr;
    const unsigned hw = w[2 * (tid & 15) + 1];
    const bool is64 = (__ballot(hw == 0u) == ~0ull);
    __syncthreads();
    const int e0 = (b * 256 + tid) * 4;  // N_EDGES % 4 == 0
    unsigned sd[4];
    int ne = 0;
    if (e0 < N_EDGES) {
      if (is64) {
        const long long* p = (const long long*)eptr;
#pragma unroll
        for (int j = 0; j < 4; ++j)
          sd[j] = (unsigned)p[e0 + j] | ((unsigned)p[N_EDGES + e0 + j] << 16);
      } else {
        const unsigned* p = (const unsigned*)eptr;
#pragma unroll
        for (int j = 0; j < 4; ++j)
          sd[j] = p[e0 + j] | (p[N_EDGES + e0 + j] << 16);
      }
      ne = 4;
    }
    for (int j = 0; j < ne; ++j) {
      const int d = (int)(sd[j] >> 16);
      const int g = d / GRPN;
      const int pos = atomicAdd(&lcnt[g], 1);
      if (pos < 256) {
        stage[g][pos] = sd[j];
      } else {  // overflow fallback (P ~ 1e-29)
        const int gp = atomicAdd(&bukCnt[g], 1);
        if (gp < BCAP) ebuk[(size_t)g * BCAP + gp] = sd[j];
      }
    }
    __syncthreads();
    if (tid < NGRP) gbase[tid] = atomicAdd(&bukCnt[tid], min(lcnt[tid], 256));
    __syncthreads();
#pragma unroll
    for (int g = 0; g < NGRP; ++g) {
      const int c = min(lcnt[g], 256);
      for (int i = tid; i < c; i += 256) {
        const int gp = gbase[g] + i;
        if (gp < BCAP) ebuk[(size_t)g * BCAP + gp] = stage[g][i];
      }
    }
  } else if (b < CONV_BLOCKS + X2B_BLOCKS) {
    const int i = (b - CONV_BLOCKS) * 256 + tid;  // 8 floats each, exact
    const float4 v0 = ((const float4*)x)[2 * i];
    const float4 v1 = ((const float4*)x)[2 * i + 1];
    uint4v o;
    o[0] = pack2(v0.x, v0.y);
    o[1] = pack2(v0.z, v0.w);
    o[2] = pack2(v1.x, v1.y);
    o[3] = pack2(v1.z, v1.w);
    ((uint4v*)xb)[i] = o;
  } else if (b < CONV_BLOCKS + X2B_BLOCKS + CNT_BLOCKS) {
    const int i = (b - CONV_BLOCKS - X2B_BLOCKS) * 256 + tid;
    if (i < N_NODES / 4) {
      uint4v z = {0u, 0u, 0u, 0u};
      ((uint4v*)cnt)[i] = z;
    }
  } else {
    const int i = (b - CONV_BLOCKS - X2B_BLOCKS - CNT_BLOCKS) * 256 + tid;
    if (i < 2 * DIM * DIM) {
      const float* W = (i < DIM * DIM) ? W1 : W2;
      unsigned short* Wt = (i < DIM * DIM) ? wt1 : wt2;
      const int j = i & (DIM * DIM - 1);
      const int c = j >> 7, k = j & 127;
      Wt[c * DIM + k] = f2bf(W[k * DIM + c]);
    } else {
      const int j = i - 2 * DIM * DIM;  // 0..8191
      const int k = j >> 6, h = j & 63;
      wh1t[h * DIM + k] = f2bf(Wh1[k * 64 + h]);
    }
  }
}

// ---------------------------------------------------------------------------
// Bucketed padded scatter: group g = blockIdx&7 reads only bucket g and owns
// dst range [g*6250,(g+1)*6250) -> per-XCD working set ~1.2 MB.
// ---------------------------------------------------------------------------
__global__ __launch_bounds__(256) void k_scatter(
    const unsigned* __restrict__ ebuk, const int* __restrict__ bukCnt,
    int* __restrict__ cnt, unsigned short* __restrict__ csrp) {
  const int grp = blockIdx.x & (NGRP - 1);
  const int slice = blockIdx.x >> 3;
  const int nE = min(bukCnt[grp], BCAP);
  const int CH = (nE + BPG - 1) / BPG;
  const int i0 = slice * CH;
  const int i1 = min(i0 + CH, nE);
  const unsigned* src = ebuk + (size_t)grp * BCAP;
  for (int i = i0 + (int)threadIdx.x; i < i1; i += 256) {
    const unsigned sd = src[i];
    const int d = (int)(sd >> 16);
    const int pos = atomicAdd(&cnt[d], 1);
    if (pos < CAP) csrp[(size_t)d * CAP + pos] = (unsigned short)(sd & 0xffffu);
  }
}

// ---------------------------------------------------------------------------
// M[i,:] = (H[i,:] + sum_{j in N(i)} H[j,:]) / (deg+1), bf16 in/out,
// ROW-MAJOR (round-9 proven version; near gather-path roofline:
// 82 MB compulsory L2 fills @ ~2.4 TB/s).
// ---------------------------------------------------------------------------
__global__ __launch_bounds__(256) void k_agg(
    const unsigned* __restrict__ Hb, const unsigned short* __restrict__ csrp,
    const int* __restrict__ cnt, unsigned* __restrict__ Mb) {
  const int node = blockIdx.x * 4 + (threadIdx.x >> 6);  // grid = N/4 exact
  const int lane = threadIdx.x & 63;
  const unsigned self = Hb[(size_t)node * 64 + lane];
  float ax = bf_lo(self), ay = bf_hi(self);
  const int c = cnt[node];
  const int e = min(c, CAP);
  const unsigned short* lst = csrp + (size_t)node * CAP;
  int k = 0;
  for (; k + 8 <= e; k += 8) {
    const uint4 c8 = *(const uint4*)(lst + k);
    const int n0 = c8.x & 0xffff, n1 = c8.x >> 16;
    const int n2 = c8.y & 0xffff, n3 = c8.y >> 16;
    const int n4 = c8.z & 0xffff, n5 = c8.z >> 16;
    const int n6 = c8.w & 0xffff, n7 = c8.w >> 16;
    const unsigned v0 = Hb[(size_t)n0 * 64 + lane];
    const unsigned v1 = Hb[(size_t)n1 * 64 + lane];
    const unsigned v2 = Hb[(size_t)n2 * 64 + lane];
    const unsigned v3 = Hb[(size_t)n3 * 64 + lane];
    const unsigned v4 = Hb[(size_t)n4 * 64 + lane];
    const unsigned v5 = Hb[(size_t)n5 * 64 + lane];
    const unsigned v6 = Hb[(size_t)n6 * 64 + lane];
    const unsigned v7 = Hb[(size_t)n7 * 64 + lane];
    ax += bf_lo(v0) + bf_lo(v1) + bf_lo(v2) + bf_lo(v3) + bf_lo(v4) +
          bf_lo(v5) + bf_lo(v6) + bf_lo(v7);
    ay += bf_hi(v0) + bf_hi(v1) + bf_hi(v2) + bf_hi(v3) + bf_hi(v4) +
          bf_hi(v5) + bf_hi(v6) + bf_hi(v7);
  }
  for (; k < e; ++k) {
    const unsigned v = Hb[(size_t)lst[k] * 64 + lane];
    ax += bf_lo(v);
    ay += bf_hi(v);
  }
  const float id = 1.0f / (float)(c + 1);
  Mb[(size_t)node * 64 + lane] = pack2(ax * id, ay * id);
}

// ---------------------------------------------------------------------------
// Layer-1 GEMM: H = relu(M @ W + b) via v_mfma_f32_16x16x32_bf16, row-major.
// C/D: col = lane&15, row = 4*(lane>>4)+reg   [m89-verified layout]
// ---------------------------------------------------------------------------
__global__ __launch_bounds__(256) void k_gemm_mfma(
    const unsigned short* __restrict__ Mb, const unsigned short* __restrict__ Wt,
    const float* __restrict__ bias, unsigned short* __restrict__ Hb, int n) {
  const int lane = threadIdx.x & 63;
  const int wid = threadIdx.x >> 6;
  const int row0 = blockIdx.x * 64 + wid * 16;
  const int l15 = lane & 15;
  const int lg = lane >> 4;

  f32x4 acc[8];
#pragma unroll
  for (int t = 0; t < 8; ++t) {
    const float b = bias[t * 16 + l15];
    acc[t][0] = b; acc[t][1] = b; acc[t][2] = b; acc[t][3] = b;
  }

  const int arow = min(row0 + l15, n - 1);
  const unsigned short* aptr = Mb + (size_t)arow * DIM + lg * 8;
  const unsigned short* bbase = Wt + l15 * DIM + lg * 8;

#pragma unroll
  for (int ks = 0; ks < 4; ++ks) {
    const bf16x8 a = *(const bf16x8*)(aptr + ks * 32);
#pragma unroll
    for (int t = 0; t < 8; ++t) {
      const bf16x8 b = *(const bf16x8*)(bbase + t * 16 * DIM + ks * 32);
      acc[t] = __builtin_amdgcn_mfma_f32_16x16x32_bf16(a, b, acc[t], 0, 0, 0);
    }
  }

  const int orow0 = row0 + lg * 4;
#pragma unroll
  for (int r = 0; r < 4; ++r) {
    const int row = orow0 + r;
    if (row < n) {
#pragma unroll
      for (int t = 0; t < 8; ++t) {
        Hb[(size_t)row * DIM + t * 16 + l15] = f2bf(fmaxf(acc[t][r], 0.f));
      }
    }
  }
}

// ---------------------------------------------------------------------------
// FUSED layer-2 GEMM + head:
//   H = relu(M @ W2 + b2)            (32 MFMA, H kept on-chip)
//   H -> LDS (wave-private 16x128 tile, pad 136 u16 -> ~2-way read conflict)
//   P = relu(H @ Wh1 + bh1)          (16 MFMA via pre-transposed bf16 Wh1)
//   adj = P @ Wh2 + bh2              (4 fmul + shfl_xor reduce over 16 lanes)
//   out = alpha*scores + (1-alpha)*adj
// Saves 25.6 MB of hb round-trip + the k_head launch (round-11 lesson: keep
// unroll small, no runtime-indexed arrays -> no spill).
// ---------------------------------------------------------------------------
__global__ __launch_bounds__(256) void k_gemm_head(
    const unsigned short* __restrict__ Mb, const unsigned short* __restrict__ Wt,
    const float* __restrict__ bias, const unsigned short* __restrict__ Wh1t,
    const float* __restrict__ bh1, const float* __restrict__ Wh2,
    const float* __restrict__ bh2, const float* __restrict__ scores,
    const float* __restrict__ alpha_logit, float* __restrict__ out, int n) {
  __shared__ alignas(16) unsigned short Hl[4][16 * 136];
  const int lane = threadIdx.x & 63;
  const int wid = threadIdx.x >> 6;
  const int row0 = blockIdx.x * 64 + wid * 16;
  const int l15 = lane & 15;
  const int lg = lane >> 4;

  // ---- phase 1: H = relu(M @ W2 + b2), 16 rows x 128 cols in regs ----
  f32x4 acc[8];
#pragma unroll
  for (int t = 0; t < 8; ++t) {
    const float b = bias[t * 16 + l15];
    acc[t][0] = b; acc[t][1] = b; acc[t][2] = b; acc[t][3] = b;
  }
  const int arow = min(row0 + l15, n - 1);
  const unsigned short* aptr = Mb + (size_t)arow * DIM + lg * 8;
  const unsigned short* bbase = Wt + l15 * DIM + lg * 8;
#pragma unroll
  for (int ks = 0; ks < 4; ++ks) {
    const bf16x8 a = *(const bf16x8*)(aptr + ks * 32);
#pragma unroll
    for (int t = 0; t < 8; ++t) {
      const bf16x8 b = *(const bf16x8*)(bbase + t * 16 * DIM + ks * 32);
      acc[t] = __builtin_amdgcn_mfma_f32_16x16x32_bf16(a, b, acc[t], 0, 0, 0);
    }
  }

  // ---- H tile -> LDS (wave-private; pad to 136 u16/row) ----
  unsigned short* hl = Hl[wid];
#pragma unroll
  for (int r = 0; r < 4; ++r) {
    const int rl = lg * 4 + r;
#pragma unroll
    for (int t = 0; t < 8; ++t)
      hl[rl * 136 + t * 16 + l15] = f2bf(fmaxf(acc[t][r], 0.f));
  }
  __syncthreads();

  // ---- phase 2: P = relu(H @ Wh1 + bh1), 16 rows x 64 cols, K=128 ----
  f32x4 acc2[4];
#pragma unroll
  for (int t2 = 0; t2 < 4; ++t2) {
    const float b = bh1[t2 * 16 + l15];
    acc2[t2][0] = b; acc2[t2][1] = b; acc2[t2][2] = b; acc2[t2][3] = b;
  }
  const unsigned short* arow2 = hl + l15 * 136 + lg * 8;
  const unsigned short* bbase2 = Wh1t + l15 * DIM + lg * 8;
#pragma unroll
  for (int ks = 0; ks < 4; ++ks) {
    const bf16x8 a2 = *(const bf16x8*)(arow2 + ks * 32);
#pragma unroll
    for (int t2 = 0; t2 < 4; ++t2) {
      const bf16x8 b2 = *(const bf16x8*)(bbase2 + t2 * 16 * DIM + ks * 32);
      acc2[t2] = __builtin_amdgcn_mfma_f32_16x16x32_bf16(a2, b2, acc2[t2], 0, 0, 0);
    }
  }

  // ---- phase 3: adj = P @ Wh2 + bh2; blend with scores ----
  const float alpha = 1.0f / (1.0f + __expf(-alpha_logit[0]));
  const float beta = 1.0f - alpha;
  const float bias2 = bh2[0];
  float w2s0 = Wh2[l15], w2s1 = Wh2[16 + l15], w2s2 = Wh2[32 + l15],
        w2s3 = Wh2[48 + l15];
#pragma unroll
  for (int r = 0; r < 4; ++r) {
    float s = fmaxf(acc2[0][r], 0.f) * w2s0 + fmaxf(acc2[1][r], 0.f) * w2s1 +
              fmaxf(acc2[2][r], 0.f) * w2s2 + fmaxf(acc2[3][r], 0.f) * w2s3;
    s += __shfl_xor(s, 1);
    s += __shfl_xor(s, 2);
    s += __shfl_xor(s, 4);
    s += __shfl_xor(s, 8);
    const int row = row0 + lg * 4 + r;
    if (l15 == 0 && row < n)
      out[row] = alpha * scores[row] + beta * (s + bias2);
  }
}

extern "C" void kernel_launch(void* const* d_in, const int* in_sizes, int n_in,
                              void* d_out, int out_size, void* d_ws,
                              size_t ws_size, hipStream_t stream) {
  const float* x      = (const float*)d_in[0];
  const void*  eidx   = d_in[1];
  const float* scores = (const float*)d_in[2];
  const float* W1     = (const float*)d_in[3];
  const float* b1     = (const float*)d_in[4];
  const float* W2     = (const float*)d_in[5];
  const float* b2     = (const float*)d_in[6];
  const float* Wh1    = (const float*)d_in[7];
  const float* bh1    = (const float*)d_in[8];
  const float* Wh2    = (const float*)d_in[9];
  const float* bh2    = (const float*)d_in[10];
  const float* alog   = (const float*)d_in[11];
  float* out = (float*)d_out;

  char* ws = (char*)d_ws;
  size_t off = 0;
  auto carve = [&](size_t bytes) -> char* {
    off = (off + 255) & ~(size_t)255;
    char* p = ws + off;
    off += bytes;
    return p;
  };
  unsigned short* csrp = (unsigned short*)carve((size_t)N_NODES * CAP * 2);
  unsigned* ebuk = (unsigned*)carve((size_t)NGRP * BCAP * 4);
  int*   bukCnt  = (int*)carve(NGRP * 4);
  int*   cnt     = (int*)carve((size_t)N_NODES * 4);
  unsigned* xb   = (unsigned*)carve((size_t)N_NODES * DIM * 2);
  unsigned* mb   = (unsigned*)carve((size_t)N_NODES * DIM * 2);
  unsigned* hb   = (unsigned*)carve((size_t)N_NODES * DIM * 2);
  unsigned short* wt1  = (unsigned short*)carve((size_t)DIM * DIM * 2);
  unsigned short* wt2  = (unsigned short*)carve((size_t)DIM * DIM * 2);
  unsigned short* wh1t = (unsigned short*)carve((size_t)DIM * 64 * 2);

  k_zero<<<1, 64, 0, stream>>>(bukCnt);
  k_prep<<<PREP_BLOCKS, 256, 0, stream>>>(eidx, ebuk, bukCnt, x, xb, cnt, W1,
                                          W2, Wh1, wt1, wt2, wh1t);
  k_scatter<<<NGRP * BPG, 256, 0, stream>>>(ebuk, bukCnt, cnt, csrp);

  const int ablocks = N_NODES / 4;           // 12500
  const int gblocks = (N_NODES + 63) / 64;   // 782

  k_agg<<<ablocks, 256, 0, stream>>>(xb, csrp, cnt, mb);
  k_gemm_mfma<<<gblocks, 256, 0, stream>>>((const unsigned short*)mb, wt1, b1,
                                           (unsigned short*)hb, N_NODES);
  k_agg<<<ablocks, 256, 0, stream>>>(hb, csrp, cnt, mb);
  k_gemm_head<<<gblocks, 256, 0, stream>>>((const unsigned short*)mb, wt2, b2,
                                           wh1t, bh1, Wh2, bh2, scores, alog,
                                           out, N_NODES);
}